// Round 2
// baseline (2010.875 us; speedup 1.0000x reference)
//
#include <hip/hip_runtime.h>

// Problem constants (B=8, T=16, L=1024, D=256, K=128)
#define NBT   128      // B*T

__device__ __forceinline__ float4 ld4(const float* p) { return *(const float4*)p; }

// sel/out offset for (row r in [0,1024) = b*128+k, time t): ((b*16+t)*128+k)*256
__device__ __forceinline__ int selOff(int r, int t) {
  return (((r >> 7) * 16 + t) * 128 + (r & 127)) * 256;
}

// ---------------- prologue ----------------

// one wave per (b,t,l) row: dot(x_row, w_q_sig) and dot(x_row, w_k_sig)
__global__ __launch_bounds__(256) void sig_kernel(const float* __restrict__ x,
    const float* __restrict__ wq, const float* __restrict__ wk,
    float* __restrict__ sq, float* __restrict__ sk) {
  int tid = threadIdx.x;
  int row = blockIdx.x * 4 + (tid >> 6);   // [0, 131072)
  int lane = tid & 63;
  float4 xv = ld4(x + (size_t)row * 256 + lane * 4);
  float4 a = ld4(wq + lane * 4);
  float4 b = ld4(wk + lane * 4);
  float dq = xv.x * a.x + xv.y * a.y + xv.z * a.z + xv.w * a.w;
  float dk = xv.x * b.x + xv.y * b.y + xv.z * b.z + xv.w * b.w;
  #pragma unroll
  for (int o = 32; o > 0; o >>= 1) {
    dq += __shfl_xor(dq, o, 64);
    dk += __shfl_xor(dk, o, 64);
  }
  if (lane == 0) { sq[row] = dq; sk[row] = dk; }
}

// one block per (b,t): full bitonic sort of 1024 keys (value desc, index asc), emit top 128 idx
__global__ __launch_bounds__(256) void topk_kernel(const float* __restrict__ sq,
    const float* __restrict__ sk, int* __restrict__ idx) {
  __shared__ unsigned long long keys[1024];
  int bt = blockIdx.x;
  int t = bt & 15;
  int tp = (t + 15) & 15;                  // roll(x,1,axis=1): k_sig at t uses x[t-1]
  const float* q = sq + bt * 1024;
  const float* kk = sk + (bt - t + tp) * 1024;
  for (int l = threadIdx.x; l < 1024; l += 256) {
    float v = q[l] * kk[l];                // positive pow2 scale (1/16) cannot change order
    unsigned u = __float_as_uint(v);
    unsigned s = (u & 0x80000000u) ? ~u : (u | 0x80000000u);  // monotonic float->uint
    keys[l] = ((unsigned long long)(~s) << 32) | (unsigned long long)l;
  }
  __syncthreads();
  for (int k = 2; k <= 1024; k <<= 1) {
    for (int j = k >> 1; j > 0; j >>= 1) {
      #pragma unroll
      for (int base = 0; base < 1024; base += 256) {
        int i = base + threadIdx.x;
        int ixj = i ^ j;
        if (ixj > i) {
          unsigned long long a = keys[i], b = keys[ixj];
          bool up = ((i & k) == 0);
          if ((a > b) == up) { keys[i] = b; keys[ixj] = a; }
        }
      }
      __syncthreads();
    }
  }
  if (threadIdx.x < 128)
    idx[bt * 128 + threadIdx.x] = (int)(keys[threadIdx.x] & 0xffffffffu);
}

// one wave per (b,t,k): sel = gather(x, idx); also out[:,0] = sel[:,0]
__global__ __launch_bounds__(256) void gather_kernel(const float* __restrict__ x,
    const int* __restrict__ idx, float* __restrict__ sel, float* __restrict__ out) {
  int tid = threadIdx.x;
  int row = blockIdx.x * 4 + (tid >> 6);   // [0, 16384)
  int lane = tid & 63;
  int bt = row >> 7;
  int j = idx[row];
  float4 v = ld4(x + ((size_t)bt * 1024 + j) * 256 + lane * 4);
  *(float4*)(sel + (size_t)row * 256 + lane * 4) = v;
  if ((bt & 15) == 0)
    *(float4*)(out + (size_t)row * 256 + lane * 4) = v;
}

// ---------------- per-step phase A: enc->gelu->h->qh (blocks 0..127), kh+vh (blocks 128..255) ----------------
__global__ __launch_bounds__(256) void stepA_kernel(
    const float* __restrict__ sel, const float* __restrict__ vel,
    const float* __restrict__ pinn, const float* __restrict__ psud,
    const float* __restrict__ W_enc, const float* __restrict__ b_enc,
    const float* __restrict__ W_q, const float* __restrict__ W_k,
    const float* __restrict__ W_v,
    float* __restrict__ qh, float* __restrict__ kh, float* __restrict__ vh, int t) {
  __shared__ float A[8][512];
  int tid = threadIdx.x;
  bool enc = blockIdx.x < 128;
  int r0 = (blockIdx.x & 127) * 8;

  { // build A rows: enc_in = [innov | vel], dec_kv = [innov - pinn | psud]
    int rr = tid >> 5;
    int r = r0 + rr;
    int c = (tid & 31) * 4;
    #pragma unroll
    for (int p = 0; p < 2; ++p) {
      int cc = c + p * 128;
      float4 ob = ld4(sel + selOff(r, t) + cc);
      float4 pa = ld4(sel + selOff(r, t - 1) + cc);
      float4 ve = make_float4(0.f, 0.f, 0.f, 0.f);
      if (t > 1) ve = ld4(vel + r * 256 + cc);   // initial carry is zeros (scan init)
      float4 in4;   // innov = obs - (prev_assoc + vel)
      in4.x = ob.x - (pa.x + ve.x); in4.y = ob.y - (pa.y + ve.y);
      in4.z = ob.z - (pa.z + ve.z); in4.w = ob.w - (pa.w + ve.w);
      if (enc) {
        *(float4*)&A[rr][cc] = in4;
        *(float4*)&A[rr][256 + cc] = ve;   // state_evol_diff == vel algebraically
      } else {
        float4 dv = in4, ps = make_float4(0.f, 0.f, 0.f, 0.f);
        if (t > 1) {
          float4 pi = ld4(pinn + r * 256 + cc);
          ps = ld4(psud + r * 256 + cc);
          dv.x -= pi.x; dv.y -= pi.y; dv.z -= pi.z; dv.w -= pi.w;
        }
        *(float4*)&A[rr][cc] = dv;
        *(float4*)&A[rr][256 + cc] = ps;
      }
    }
  }
  __syncthreads();
  int rg = tid >> 6;          // rows rg*2, rg*2+1
  int c4 = (tid & 63) * 4;
  if (enc) {
    float acc0[4] = {0,0,0,0}, acc1[4] = {0,0,0,0};
    for (int k = 0; k < 512; k += 4) {
      float4 a0 = *(const float4*)&A[rg * 2][k];
      float4 a1 = *(const float4*)&A[rg * 2 + 1][k];
      const float* a0p = (const float*)&a0;
      const float* a1p = (const float*)&a1;
      #pragma unroll
      for (int kk = 0; kk < 4; ++kk) {
        float4 w = ld4(W_enc + (k + kk) * 256 + c4);
        float x0 = a0p[kk], x1 = a1p[kk];
        acc0[0] += x0 * w.x; acc0[1] += x0 * w.y; acc0[2] += x0 * w.z; acc0[3] += x0 * w.w;
        acc1[0] += x1 * w.x; acc1[1] += x1 * w.y; acc1[2] += x1 * w.z; acc1[3] += x1 * w.w;
      }
    }
    float4 be = ld4(b_enc + c4);
    const float* bep = (const float*)&be;
    float h0[4], h1[4];
    #pragma unroll
    for (int i = 0; i < 4; ++i) {   // jax.nn.gelu default approximate=True (tanh form)
      float v0 = acc0[i] + bep[i];
      float v1 = acc1[i] + bep[i];
      float u0 = 0.7978845608028654f * (v0 + 0.044715f * v0 * v0 * v0);
      float u1 = 0.7978845608028654f * (v1 + 0.044715f * v1 * v1 * v1);
      h0[i] = 0.5f * v0 * (1.f + tanhf(u0));
      h1[i] = 0.5f * v1 * (1.f + tanhf(u1));
    }
    __syncthreads();
    *(float4*)&A[rg * 2][c4] = *(float4*)h0;       // reuse A buffer for h
    *(float4*)&A[rg * 2 + 1][c4] = *(float4*)h1;
    __syncthreads();
    float q0[4] = {0,0,0,0}, q1[4] = {0,0,0,0};
    for (int k = 0; k < 256; k += 4) {
      float4 a0 = *(const float4*)&A[rg * 2][k];
      float4 a1 = *(const float4*)&A[rg * 2 + 1][k];
      const float* a0p = (const float*)&a0;
      const float* a1p = (const float*)&a1;
      #pragma unroll
      for (int kk = 0; kk < 4; ++kk) {
        float4 w = ld4(W_q + (k + kk) * 256 + c4);
        float x0 = a0p[kk], x1 = a1p[kk];
        q0[0] += x0 * w.x; q0[1] += x0 * w.y; q0[2] += x0 * w.z; q0[3] += x0 * w.w;
        q1[0] += x1 * w.x; q1[1] += x1 * w.y; q1[2] += x1 * w.z; q1[3] += x1 * w.w;
      }
    }
    *(float4*)(qh + (r0 + rg * 2) * 256 + c4) = *(float4*)q0;
    *(float4*)(qh + (r0 + rg * 2 + 1) * 256 + c4) = *(float4*)q1;
  } else {
    float k0[4] = {0,0,0,0}, k1[4] = {0,0,0,0}, v0[4] = {0,0,0,0}, v1[4] = {0,0,0,0};
    for (int k = 0; k < 512; k += 4) {
      float4 a0 = *(const float4*)&A[rg * 2][k];
      float4 a1 = *(const float4*)&A[rg * 2 + 1][k];
      const float* a0p = (const float*)&a0;
      const float* a1p = (const float*)&a1;
      #pragma unroll
      for (int kk = 0; kk < 4; ++kk) {
        float4 wk4 = ld4(W_k + (k + kk) * 256 + c4);
        float4 wv4 = ld4(W_v + (k + kk) * 256 + c4);
        float x0 = a0p[kk], x1 = a1p[kk];
        k0[0] += x0 * wk4.x; k0[1] += x0 * wk4.y; k0[2] += x0 * wk4.z; k0[3] += x0 * wk4.w;
        k1[0] += x1 * wk4.x; k1[1] += x1 * wk4.y; k1[2] += x1 * wk4.z; k1[3] += x1 * wk4.w;
        v0[0] += x0 * wv4.x; v0[1] += x0 * wv4.y; v0[2] += x0 * wv4.z; v0[3] += x0 * wv4.w;
        v1[0] += x1 * wv4.x; v1[1] += x1 * wv4.y; v1[2] += x1 * wv4.z; v1[3] += x1 * wv4.w;
      }
    }
    *(float4*)(kh + (r0 + rg * 2) * 256 + c4) = *(float4*)k0;
    *(float4*)(kh + (r0 + rg * 2 + 1) * 256 + c4) = *(float4*)k1;
    *(float4*)(vh + (r0 + rg * 2) * 256 + c4) = *(float4*)v0;
    *(float4*)(vh + (r0 + rg * 2 + 1) * 256 + c4) = *(float4*)v1;
  }
}

// ---------------- per-step fused phase B+C: scores -> softmax -> ctx -> W_out -> Kalman update ----------------
__global__ __launch_bounds__(256) void stepBC_kernel(const float* __restrict__ qh,
    const float* __restrict__ khg, const float* __restrict__ vhg,
    const float* __restrict__ W_out, const float* __restrict__ b_out,
    const float* __restrict__ sel, float* __restrict__ vel,
    float* __restrict__ pinn, float* __restrict__ psud,
    float* __restrict__ out, int t) {
  __shared__ float q_lds[8][256];   // scores-phase q; reused as ctx buffer afterwards
  __shared__ float kh_t[32][260];   // +4 pad: keeps float4 alignment, spreads banks
  __shared__ float P[8][128];
  int tid = threadIdx.x;
  int bb = blockIdx.x >> 4;         // batch
  int rg = blockIdx.x & 15;         // row-group of 8 q-rows
  int r0 = bb * 128 + rg * 8;
  {
    int rr = tid >> 5;
    int c = (tid & 31) * 4;
    #pragma unroll
    for (int p = 0; p < 2; ++p) {
      int cc = c + p * 128;
      *(float4*)&q_lds[rr][cc] = ld4(qh + (r0 + rr) * 256 + cc);
    }
  }
  int r = tid >> 5;                 // q-row 0..7
  int mm = tid & 31;                // m within tile
  float s[4];
  for (int mt = 0; mt < 4; ++mt) {
    if (mt) __syncthreads();
    {
      int mi = tid >> 3;
      int cb = (tid & 7) * 4;
      const float* src = khg + (bb * 128 + mt * 32 + mi) * 256;
      #pragma unroll
      for (int p = 0; p < 8; ++p) {
        int cc = cb + p * 32;
        *(float4*)&kh_t[mi][cc] = ld4(src + cc);
      }
    }
    __syncthreads();
    float acc = 0.f;
    for (int k = 0; k < 256; k += 4) {
      float4 qv = *(const float4*)&q_lds[r][k];
      float4 kv = *(const float4*)&kh_t[mm][k];
      acc += qv.x * kv.x + qv.y * kv.y + qv.z * kv.z + qv.w * kv.w;
    }
    s[mt] = acc * 0.0625f;          // * 1/sqrt(256)
  }
  // softmax across 128 m (4 regs x 32 lanes; shfl stays within 32-lane r-group)
  float mx = fmaxf(fmaxf(s[0], s[1]), fmaxf(s[2], s[3]));
  #pragma unroll
  for (int o = 16; o > 0; o >>= 1) mx = fmaxf(mx, __shfl_xor(mx, o, 64));
  float e0 = expf(s[0] - mx), e1 = expf(s[1] - mx), e2 = expf(s[2] - mx), e3 = expf(s[3] - mx);
  float sum = e0 + e1 + e2 + e3;
  #pragma unroll
  for (int o = 16; o > 0; o >>= 1) sum += __shfl_xor(sum, o, 64);
  float inv = 1.f / sum;
  P[r][mm]      = e0 * inv;
  P[r][32 + mm] = e1 * inv;
  P[r][64 + mm] = e2 * inv;
  P[r][96 + mm] = e3 * inv;
  __syncthreads();
  // ctx = P @ vh : thread = (row r, 8 cols starting at mm*8)
  int c8 = mm * 8;
  float a[8] = {0,0,0,0,0,0,0,0};
  const float* vb = vhg + bb * 128 * 256;
  for (int m = 0; m < 128; ++m) {
    float p = P[r][m];
    float4 va = ld4(vb + m * 256 + c8);
    float4 vc = ld4(vb + m * 256 + c8 + 4);
    a[0] += p * va.x; a[1] += p * va.y; a[2] += p * va.z; a[3] += p * va.w;
    a[4] += p * vc.x; a[5] += p * vc.y; a[6] += p * vc.z; a[7] += p * vc.w;
  }
  // stash ctx into q_lds (q is dead after the scores phase); disjoint from P/kh_t
  *(float4*)&q_lds[r][c8]     = *(float4*)&a[0];
  *(float4*)&q_lds[r][c8 + 4] = *(float4*)&a[4];
  __syncthreads();
  // ---- fused stepC: gate = sigmoid(ctx @ W_out + b_out), Kalman update ----
  // thread = (row rr, 8 cols at cc); rr = tid>>5 spans 2 values per wave (fine)
  int rr = tid >> 5;
  int cc = (tid & 31) * 8;
  float acc8[8] = {0,0,0,0,0,0,0,0};
  for (int k = 0; k < 256; k += 4) {
    float4 cv = *(const float4*)&q_lds[rr][k];
    const float* cp = (const float*)&cv;
    #pragma unroll
    for (int kk = 0; kk < 4; ++kk) {
      float4 w0 = ld4(W_out + (k + kk) * 256 + cc);
      float4 w1 = ld4(W_out + (k + kk) * 256 + cc + 4);
      float xv = cp[kk];
      acc8[0] += xv * w0.x; acc8[1] += xv * w0.y; acc8[2] += xv * w0.z; acc8[3] += xv * w0.w;
      acc8[4] += xv * w1.x; acc8[5] += xv * w1.y; acc8[6] += xv * w1.z; acc8[7] += xv * w1.w;
    }
  }
  int row = r0 + rr;
  #pragma unroll
  for (int p = 0; p < 2; ++p) {
    int cp4 = cc + p * 4;
    float4 bo = ld4(b_out + cp4);
    const float* bop = (const float*)&bo;
    float4 ob = ld4(sel + selOff(row, t) + cp4);
    float4 pa = ld4(sel + selOff(row, t - 1) + cp4);
    float4 ve = make_float4(0.f, 0.f, 0.f, 0.f);
    int off = row * 256 + cp4;
    if (t > 1) ve = ld4(vel + off);
    const float* obp = (const float*)&ob;
    const float* pap = (const float*)&pa;
    const float* vep = (const float*)&ve;
    float inn[4], upd[4], ov[4], nv[4];
    #pragma unroll
    for (int i = 0; i < 4; ++i) {
      float g = 1.f / (1.f + expf(-(acc8[p * 4 + i] + bop[i])));
      float pr = pap[i] + vep[i];            // pred
      float in_ = obp[i] - pr;               // innov
      float up = g * in_;                    // Kg*innov
      inn[i] = in_; upd[i] = up;
      ov[i] = pr + up;                       // x_post
      nv[i] = vep[i] + up;                   // new_vel
    }
    *(float4*)(out + selOff(row, t) + cp4) = *(float4*)ov;
    *(float4*)(pinn + off) = *(float4*)inn;
    *(float4*)(psud + off) = *(float4*)upd;
    *(float4*)(vel + off)  = *(float4*)nv;
  }
}

// ---------------- launch ----------------
extern "C" void kernel_launch(void* const* d_in, const int* in_sizes, int n_in,
                              void* d_out, int out_size, void* d_ws, size_t ws_size,
                              hipStream_t stream) {
  const float* x      = (const float*)d_in[0];
  const float* wq_sig = (const float*)d_in[1];
  const float* wk_sig = (const float*)d_in[2];
  const float* W_enc  = (const float*)d_in[3];
  const float* b_enc  = (const float*)d_in[4];
  const float* W_q    = (const float*)d_in[5];
  const float* W_k    = (const float*)d_in[6];
  const float* W_v    = (const float*)d_in[7];
  const float* W_out  = (const float*)d_in[8];
  const float* b_out  = (const float*)d_in[9];
  float* out = (float*)d_out;

  float* ws = (float*)d_ws;
  float* sq   = ws;                    // 131072
  float* sk   = ws + 131072;           // 131072
  float* sel  = ws + 262144;           // 4194304
  float* vel  = ws + 4456448;          // 262144
  float* pinn = ws + 4718592;          // 262144
  float* psud = ws + 4980736;          // 262144
  float* qh   = ws + 5242880;          // 262144
  float* kh   = ws + 5505024;          // 262144
  float* vh   = ws + 5767168;          // 262144
  int*   idx  = (int*)(ws + 6029312);  // 16384 ints

  // no memset needed: t==1 kernels synthesize the zero initial carry in-register,
  // and vel/pinn/psud are written (stepBC t) before first read (stepA/BC t+1).
  sig_kernel<<<32768, 256, 0, stream>>>(x, wq_sig, wk_sig, sq, sk);
  topk_kernel<<<NBT, 256, 0, stream>>>(sq, sk, idx);
  gather_kernel<<<4096, 256, 0, stream>>>(x, idx, sel, out);
  for (int t = 1; t < 16; ++t) {
    stepA_kernel<<<256, 256, 0, stream>>>(sel, vel, pinn, psud, W_enc, b_enc,
                                          W_q, W_k, W_v, qh, kh, vh, t);
    stepBC_kernel<<<128, 256, 0, stream>>>(qh, kh, vh, W_out, b_out, sel,
                                           vel, pinn, psud, out, t);
  }
}

// Round 5
// 1756.802 us; speedup vs baseline: 1.1446x; 1.1446x over previous
//
#include <hip/hip_runtime.h>

// Problem constants (B=8, T=16, L=1024, D=256, K=128)
#define NBT   128      // B*T

__device__ __forceinline__ float4 ld4(const float* p) { return *(const float4*)p; }

// sel/out offset for (row r in [0,1024) = b*128+k, time t): ((b*16+t)*128+k)*256
__device__ __forceinline__ int selOff(int r, int t) {
  return (((r >> 7) * 16 + t) * 128 + (r & 127)) * 256;
}

// async global->LDS: copy 16KB linearly. 256 threads: 4 chunks x 4 waves x 64 lanes x 16B.
// dst passed wave-uniform (HW adds lane*16); src per-lane. Linear both sides.
__device__ __forceinline__ void stage16k(const float* g, float* l, int tid) {
  int wave = tid >> 6, lane = tid & 63;
  #pragma unroll
  for (int c = 0; c < 4; ++c) {
    int off = c * 4096 + wave * 1024;   // bytes
    __builtin_amdgcn_global_load_lds(
        (const __attribute__((address_space(1))) void*)((const char*)g + off + lane * 16),
        (__attribute__((address_space(3))) void*)((char*)l + off),
        16, 0, 0);
  }
}

// stage a combined dec tile: db[8][512]; row r cols 0..255 = W_k row, 256..511 = W_v row
__device__ __forceinline__ void stage_dec(const float* wk, const float* wv, float* db, int tid) {
  int wave = tid >> 6, lane = tid & 63;
  #pragma unroll
  for (int i = 0; i < 2; ++i) {
    int row = wave * 2 + i;   // 0..7, wave-uniform
    __builtin_amdgcn_global_load_lds(
        (const __attribute__((address_space(1))) void*)(wk + row * 256 + lane * 4),
        (__attribute__((address_space(3))) void*)(db + row * 512), 16, 0, 0);
    __builtin_amdgcn_global_load_lds(
        (const __attribute__((address_space(1))) void*)(wv + row * 256 + lane * 4),
        (__attribute__((address_space(3))) void*)(db + row * 512 + 256), 16, 0, 0);
  }
}

// ---------------- prologue ----------------

__global__ __launch_bounds__(256) void sig_kernel(const float* __restrict__ x,
    const float* __restrict__ wq, const float* __restrict__ wk,
    float* __restrict__ sq, float* __restrict__ sk) {
  int tid = threadIdx.x;
  int row = blockIdx.x * 4 + (tid >> 6);   // [0, 131072)
  int lane = tid & 63;
  float4 xv = ld4(x + (size_t)row * 256 + lane * 4);
  float4 a = ld4(wq + lane * 4);
  float4 b = ld4(wk + lane * 4);
  float dq = xv.x * a.x + xv.y * a.y + xv.z * a.z + xv.w * a.w;
  float dk = xv.x * b.x + xv.y * b.y + xv.z * b.z + xv.w * b.w;
  #pragma unroll
  for (int o = 32; o > 0; o >>= 1) {
    dq += __shfl_xor(dq, o, 64);
    dk += __shfl_xor(dk, o, 64);
  }
  if (lane == 0) { sq[row] = dq; sk[row] = dk; }
}

__global__ __launch_bounds__(256) void topk_kernel(const float* __restrict__ sq,
    const float* __restrict__ sk, int* __restrict__ idx) {
  __shared__ unsigned long long keys[1024];
  int bt = blockIdx.x;
  int t = bt & 15;
  int tp = (t + 15) & 15;                  // roll(x,1,axis=1): k_sig at t uses x[t-1]
  const float* q = sq + bt * 1024;
  const float* kk = sk + (bt - t + tp) * 1024;
  for (int l = threadIdx.x; l < 1024; l += 256) {
    float v = q[l] * kk[l];
    unsigned u = __float_as_uint(v);
    unsigned s = (u & 0x80000000u) ? ~u : (u | 0x80000000u);  // monotonic float->uint
    keys[l] = ((unsigned long long)(~s) << 32) | (unsigned long long)l;
  }
  __syncthreads();
  for (int k = 2; k <= 1024; k <<= 1) {
    for (int j = k >> 1; j > 0; j >>= 1) {
      #pragma unroll
      for (int base = 0; base < 1024; base += 256) {
        int i = base + threadIdx.x;
        int ixj = i ^ j;
        if (ixj > i) {
          unsigned long long a = keys[i], b = keys[ixj];
          bool up = ((i & k) == 0);
          if ((a > b) == up) { keys[i] = b; keys[ixj] = a; }
        }
      }
      __syncthreads();
    }
  }
  if (threadIdx.x < 128)
    idx[bt * 128 + threadIdx.x] = (int)(keys[threadIdx.x] & 0xffffffffu);
}

__global__ __launch_bounds__(256) void gather_kernel(const float* __restrict__ x,
    const int* __restrict__ idx, float* __restrict__ sel, float* __restrict__ out) {
  int tid = threadIdx.x;
  int row = blockIdx.x * 4 + (tid >> 6);   // [0, 16384)
  int lane = tid & 63;
  int bt = row >> 7;
  int j = idx[row];
  float4 v = ld4(x + ((size_t)bt * 1024 + j) * 256 + lane * 4);
  *(float4*)(sel + (size_t)row * 256 + lane * 4) = v;
  if ((bt & 15) == 0)
    *(float4*)(out + (size_t)row * 256 + lane * 4) = v;
}

// ---------------- per-step phase A ----------------
// blocks 0..127 (enc): h = gelu(A_enc@W_enc+b) -> qh = h@W_q   (h lives in LDS)
// blocks 128..255 (dec): kh = A_dec@W_k, vh = A_dec@W_v
// W K-tiles double-buffered in LDS via global_load_lds; one barrier per tile.
// Thread tile 2 rows x 4 cols with rp in LOW bits (tid&3): the 4 row-duplicated
// lanes of each W value share one wave -> LDS same-address broadcast (free).
__global__ __launch_bounds__(256) void stepA_kernel(
    const float* __restrict__ sel, const float* __restrict__ vel,
    const float* __restrict__ pinn, const float* __restrict__ psud,
    const float* __restrict__ W_enc, const float* __restrict__ b_enc,
    const float* __restrict__ W_q, const float* __restrict__ W_k,
    const float* __restrict__ W_v,
    float* __restrict__ qh, float* __restrict__ kh, float* __restrict__ vh, int t) {
  __shared__ __align__(16) float A[8][512];      // 16KB: A_enc/A_dec; enc reuses cols 0..255 for h
  __shared__ __align__(16) float WB[2][4096];    // 2x16KB: W tile double buffer
  int tid = threadIdx.x;
  bool enc = blockIdx.x < 128;
  int r0 = (blockIdx.x & 127) * 8;

  { // build A rows: enc_in = [innov | vel], dec_kv = [innov - pinn | psud]  (round-2 verified math)
    int rr = tid >> 5;
    int r = r0 + rr;
    int c = (tid & 31) * 4;
    #pragma unroll
    for (int p = 0; p < 2; ++p) {
      int cc = c + p * 128;
      float4 ob = ld4(sel + selOff(r, t) + cc);
      float4 pa = ld4(sel + selOff(r, t - 1) + cc);
      float4 ve = make_float4(0.f, 0.f, 0.f, 0.f);
      if (t > 1) ve = ld4(vel + r * 256 + cc);   // initial carry is zeros (scan init)
      float4 in4;   // innov = obs - (prev_assoc + vel)
      in4.x = ob.x - (pa.x + ve.x); in4.y = ob.y - (pa.y + ve.y);
      in4.z = ob.z - (pa.z + ve.z); in4.w = ob.w - (pa.w + ve.w);
      if (enc) {
        *(float4*)&A[rr][cc] = in4;
        *(float4*)&A[rr][256 + cc] = ve;   // state_evol_diff == vel algebraically
      } else {
        float4 dv = in4, ps = make_float4(0.f, 0.f, 0.f, 0.f);
        if (t > 1) {
          float4 pi = ld4(pinn + r * 256 + cc);
          ps = ld4(psud + r * 256 + cc);
          dv.x -= pi.x; dv.y -= pi.y; dv.z -= pi.z; dv.w -= pi.w;
        }
        *(float4*)&A[rr][cc] = dv;
        *(float4*)&A[rr][256 + cc] = ps;
      }
    }
  }

  int rp = tid & 3;            // row pair: rows 2rp, 2rp+1 (low bits -> in-wave W broadcast)
  int r0l = 2 * rp;
  int c4 = (tid >> 2) * 4;     // 0..252

  if (enc) {
    stage16k(W_enc, WB[0], tid);           // tile 0
    __syncthreads();                       // A visible + tile 0 ready
    float acc0[4] = {0,0,0,0}, acc1[4] = {0,0,0,0};
    for (int kt = 0; kt < 32; ++kt) {
      if (kt + 1 < 32) stage16k(W_enc + (kt + 1) * 4096, WB[(kt + 1) & 1], tid);
      const float* wt = WB[kt & 1];
      #pragma unroll
      for (int kk = 0; kk < 16; kk += 4) {
        float4 a0 = *(const float4*)&A[r0l][kt * 16 + kk];
        float4 a1 = *(const float4*)&A[r0l + 1][kt * 16 + kk];
        const float* a0p = (const float*)&a0;
        const float* a1p = (const float*)&a1;
        #pragma unroll
        for (int j = 0; j < 4; ++j) {
          float4 w = *(const float4*)&wt[(kk + j) * 256 + c4];
          float x0 = a0p[j], x1 = a1p[j];
          acc0[0] += x0 * w.x; acc0[1] += x0 * w.y; acc0[2] += x0 * w.z; acc0[3] += x0 * w.w;
          acc1[0] += x1 * w.x; acc1[1] += x1 * w.y; acc1[2] += x1 * w.z; acc1[3] += x1 * w.w;
        }
      }
      __syncthreads();   // tile kt reads done by all waves; tile kt+1 staged
    }
    // bias + gelu (tanh approx, identical to verified round-2 math)
    float4 be = ld4(b_enc + c4);
    const float* bep = (const float*)&be;
    float h0[4], h1[4];
    #pragma unroll
    for (int i = 0; i < 4; ++i) {
      float v0 = acc0[i] + bep[i];
      float v1 = acc1[i] + bep[i];
      float u0 = 0.7978845608028654f * (v0 + 0.044715f * v0 * v0 * v0);
      float u1 = 0.7978845608028654f * (v1 + 0.044715f * v1 * v1 * v1);
      h0[i] = 0.5f * v0 * (1.f + tanhf(u0));
      h1[i] = 0.5f * v1 * (1.f + tanhf(u1));
    }
    // all A reads finished at last barrier; stash h into A[.][0..255]
    *(float4*)&A[r0l][c4]     = *(float4*)h0;
    *(float4*)&A[r0l + 1][c4] = *(float4*)h1;
    stage16k(W_q, WB[0], tid);             // q tile 0 (WB[0] free: last compute used WB[1])
    __syncthreads();
    float q0[4] = {0,0,0,0}, q1[4] = {0,0,0,0};
    for (int kt = 0; kt < 16; ++kt) {
      if (kt + 1 < 16) stage16k(W_q + (kt + 1) * 4096, WB[(kt + 1) & 1], tid);
      const float* wt = WB[kt & 1];
      #pragma unroll
      for (int kk = 0; kk < 16; kk += 4) {
        float4 a0 = *(const float4*)&A[r0l][kt * 16 + kk];
        float4 a1 = *(const float4*)&A[r0l + 1][kt * 16 + kk];
        const float* a0p = (const float*)&a0;
        const float* a1p = (const float*)&a1;
        #pragma unroll
        for (int j = 0; j < 4; ++j) {
          float4 w = *(const float4*)&wt[(kk + j) * 256 + c4];
          float x0 = a0p[j], x1 = a1p[j];
          q0[0] += x0 * w.x; q0[1] += x0 * w.y; q0[2] += x0 * w.z; q0[3] += x0 * w.w;
          q1[0] += x1 * w.x; q1[1] += x1 * w.y; q1[2] += x1 * w.z; q1[3] += x1 * w.w;
        }
      }
      __syncthreads();
    }
    *(float4*)(qh + (r0 + r0l) * 256 + c4)     = *(float4*)q0;
    *(float4*)(qh + (r0 + r0l + 1) * 256 + c4) = *(float4*)q1;
  } else {
    stage_dec(W_k, W_v, WB[0], tid);       // tile 0
    __syncthreads();
    float k0[4] = {0,0,0,0}, k1[4] = {0,0,0,0}, v0[4] = {0,0,0,0}, v1[4] = {0,0,0,0};
    for (int kt = 0; kt < 64; ++kt) {
      if (kt + 1 < 64)
        stage_dec(W_k + (kt + 1) * 2048, W_v + (kt + 1) * 2048, WB[(kt + 1) & 1], tid);
      const float* db = WB[kt & 1];
      #pragma unroll
      for (int kk = 0; kk < 8; kk += 4) {
        float4 a0 = *(const float4*)&A[r0l][kt * 8 + kk];
        float4 a1 = *(const float4*)&A[r0l + 1][kt * 8 + kk];
        const float* a0p = (const float*)&a0;
        const float* a1p = (const float*)&a1;
        #pragma unroll
        for (int j = 0; j < 4; ++j) {
          float4 wk4 = *(const float4*)&db[(kk + j) * 512 + c4];
          float4 wv4 = *(const float4*)&db[(kk + j) * 512 + 256 + c4];
          float x0 = a0p[j], x1 = a1p[j];
          k0[0] += x0 * wk4.x; k0[1] += x0 * wk4.y; k0[2] += x0 * wk4.z; k0[3] += x0 * wk4.w;
          k1[0] += x1 * wk4.x; k1[1] += x1 * wk4.y; k1[2] += x1 * wk4.z; k1[3] += x1 * wk4.w;
          v0[0] += x0 * wv4.x; v0[1] += x0 * wv4.y; v0[2] += x0 * wv4.z; v0[3] += x0 * wv4.w;
          v1[0] += x1 * wv4.x; v1[1] += x1 * wv4.y; v1[2] += x1 * wv4.z; v1[3] += x1 * wv4.w;
        }
      }
      __syncthreads();
    }
    *(float4*)(kh + (r0 + r0l) * 256 + c4)     = *(float4*)k0;
    *(float4*)(kh + (r0 + r0l + 1) * 256 + c4) = *(float4*)k1;
    *(float4*)(vh + (r0 + r0l) * 256 + c4)     = *(float4*)v0;
    *(float4*)(vh + (r0 + r0l + 1) * 256 + c4) = *(float4*)v1;
  }
}

// ---------------- per-step fused phase B+C (unchanged, verified round-2) ----------------
__global__ __launch_bounds__(256) void stepBC_kernel(const float* __restrict__ qh,
    const float* __restrict__ khg, const float* __restrict__ vhg,
    const float* __restrict__ W_out, const float* __restrict__ b_out,
    const float* __restrict__ sel, float* __restrict__ vel,
    float* __restrict__ pinn, float* __restrict__ psud,
    float* __restrict__ out, int t) {
  __shared__ float q_lds[8][256];   // scores-phase q; reused as ctx buffer afterwards
  __shared__ float kh_t[32][260];
  __shared__ float P[8][128];
  int tid = threadIdx.x;
  int bb = blockIdx.x >> 4;
  int rg = blockIdx.x & 15;
  int r0 = bb * 128 + rg * 8;
  {
    int rr = tid >> 5;
    int c = (tid & 31) * 4;
    #pragma unroll
    for (int p = 0; p < 2; ++p) {
      int cc = c + p * 128;
      *(float4*)&q_lds[rr][cc] = ld4(qh + (r0 + rr) * 256 + cc);
    }
  }
  int r = tid >> 5;
  int mm = tid & 31;
  float s[4];
  for (int mt = 0; mt < 4; ++mt) {
    if (mt) __syncthreads();
    {
      int mi = tid >> 3;
      int cb = (tid & 7) * 4;
      const float* src = khg + (bb * 128 + mt * 32 + mi) * 256;
      #pragma unroll
      for (int p = 0; p < 8; ++p) {
        int cc = cb + p * 32;
        *(float4*)&kh_t[mi][cc] = ld4(src + cc);
      }
    }
    __syncthreads();
    float acc = 0.f;
    for (int k = 0; k < 256; k += 4) {
      float4 qv = *(const float4*)&q_lds[r][k];
      float4 kv = *(const float4*)&kh_t[mm][k];
      acc += qv.x * kv.x + qv.y * kv.y + qv.z * kv.z + qv.w * kv.w;
    }
    s[mt] = acc * 0.0625f;
  }
  float mx = fmaxf(fmaxf(s[0], s[1]), fmaxf(s[2], s[3]));
  #pragma unroll
  for (int o = 16; o > 0; o >>= 1) mx = fmaxf(mx, __shfl_xor(mx, o, 64));
  float e0 = expf(s[0] - mx), e1 = expf(s[1] - mx), e2 = expf(s[2] - mx), e3 = expf(s[3] - mx);
  float sum = e0 + e1 + e2 + e3;
  #pragma unroll
  for (int o = 16; o > 0; o >>= 1) sum += __shfl_xor(sum, o, 64);
  float inv = 1.f / sum;
  P[r][mm]      = e0 * inv;
  P[r][32 + mm] = e1 * inv;
  P[r][64 + mm] = e2 * inv;
  P[r][96 + mm] = e3 * inv;
  __syncthreads();
  int c8 = mm * 8;
  float a[8] = {0,0,0,0,0,0,0,0};
  const float* vb = vhg + bb * 128 * 256;
  for (int m = 0; m < 128; ++m) {
    float p = P[r][m];
    float4 va = ld4(vb + m * 256 + c8);
    float4 vc = ld4(vb + m * 256 + c8 + 4);
    a[0] += p * va.x; a[1] += p * va.y; a[2] += p * va.z; a[3] += p * va.w;
    a[4] += p * vc.x; a[5] += p * vc.y; a[6] += p * vc.z; a[7] += p * vc.w;
  }
  *(float4*)&q_lds[r][c8]     = *(float4*)&a[0];
  *(float4*)&q_lds[r][c8 + 4] = *(float4*)&a[4];
  __syncthreads();
  int rr = tid >> 5;
  int cc = (tid & 31) * 8;
  float acc8[8] = {0,0,0,0,0,0,0,0};
  for (int k = 0; k < 256; k += 4) {
    float4 cv = *(const float4*)&q_lds[rr][k];
    const float* cp = (const float*)&cv;
    #pragma unroll
    for (int kk = 0; kk < 4; ++kk) {
      float4 w0 = ld4(W_out + (k + kk) * 256 + cc);
      float4 w1 = ld4(W_out + (k + kk) * 256 + cc + 4);
      float xv = cp[kk];
      acc8[0] += xv * w0.x; acc8[1] += xv * w0.y; acc8[2] += xv * w0.z; acc8[3] += xv * w0.w;
      acc8[4] += xv * w1.x; acc8[5] += xv * w1.y; acc8[6] += xv * w1.z; acc8[7] += xv * w1.w;
    }
  }
  int row = r0 + rr;
  #pragma unroll
  for (int p = 0; p < 2; ++p) {
    int cp4 = cc + p * 4;
    float4 bo = ld4(b_out + cp4);
    const float* bop = (const float*)&bo;
    float4 ob = ld4(sel + selOff(row, t) + cp4);
    float4 pa = ld4(sel + selOff(row, t - 1) + cp4);
    float4 ve = make_float4(0.f, 0.f, 0.f, 0.f);
    int off = row * 256 + cp4;
    if (t > 1) ve = ld4(vel + off);
    const float* obp = (const float*)&ob;
    const float* pap = (const float*)&pa;
    const float* vep = (const float*)&ve;
    float inn[4], upd[4], ov[4], nv[4];
    #pragma unroll
    for (int i = 0; i < 4; ++i) {
      float g = 1.f / (1.f + expf(-(acc8[p * 4 + i] + bop[i])));
      float pr = pap[i] + vep[i];
      float in_ = obp[i] - pr;
      float up = g * in_;
      inn[i] = in_; upd[i] = up;
      ov[i] = pr + up;
      nv[i] = vep[i] + up;
    }
    *(float4*)(out + selOff(row, t) + cp4) = *(float4*)ov;
    *(float4*)(pinn + off) = *(float4*)inn;
    *(float4*)(psud + off) = *(float4*)upd;
    *(float4*)(vel + off)  = *(float4*)nv;
  }
}

// ---------------- launch ----------------
extern "C" void kernel_launch(void* const* d_in, const int* in_sizes, int n_in,
                              void* d_out, int out_size, void* d_ws, size_t ws_size,
                              hipStream_t stream) {
  const float* x      = (const float*)d_in[0];
  const float* wq_sig = (const float*)d_in[1];
  const float* wk_sig = (const float*)d_in[2];
  const float* W_enc  = (const float*)d_in[3];
  const float* b_enc  = (const float*)d_in[4];
  const float* W_q    = (const float*)d_in[5];
  const float* W_k    = (const float*)d_in[6];
  const float* W_v    = (const float*)d_in[7];
  const float* W_out  = (const float*)d_in[8];
  const float* b_out  = (const float*)d_in[9];
  float* out = (float*)d_out;

  float* ws = (float*)d_ws;
  float* sq   = ws;                    // 131072
  float* sk   = ws + 131072;           // 131072
  float* sel  = ws + 262144;           // 4194304
  float* vel  = ws + 4456448;          // 262144
  float* pinn = ws + 4718592;          // 262144
  float* psud = ws + 4980736;          // 262144
  float* qh   = ws + 5242880;          // 262144
  float* kh   = ws + 5505024;          // 262144
  float* vh   = ws + 5767168;          // 262144
  int*   idx  = (int*)(ws + 6029312);  // 16384 ints

  sig_kernel<<<32768, 256, 0, stream>>>(x, wq_sig, wk_sig, sq, sk);
  topk_kernel<<<NBT, 256, 0, stream>>>(sq, sk, idx);
  gather_kernel<<<4096, 256, 0, stream>>>(x, idx, sel, out);
  for (int t = 1; t < 16; ++t) {
    stepA_kernel<<<256, 256, 0, stream>>>(sel, vel, pinn, psud, W_enc, b_enc,
                                          W_q, W_k, W_v, qh, kh, vh, t);
    stepBC_kernel<<<128, 256, 0, stream>>>(qh, kh, vh, W_out, b_out, sel,
                                           vel, pinn, psud, out, t);
  }
}